// Round 11
// baseline (347.022 us; speedup 1.0000x reference)
//
#include <hip/hip_runtime.h>
#include <hip/hip_cooperative_groups.h>
#include <math.h>

namespace cg = cooperative_groups;

#define TEMP    0.1f
#define CEXP    -1442.6950408889634f   // -1000 * log2(e)
#define SQRTC   37.98283767f           // sqrt(1000 * log2(e))
#define LOG2E   1.4426950408889634f

// Problem: B=2,H=8 -> BH=16; N=256; L=64.  X,Y: [BH,256,64] f32. out: [BH,256,256] f32.
//
// Round 11: single persistent COOPERATIVE kernel (prep -> grid.sync -> pass1
// units -> grid.sync -> weights+wsum). Inner code identical to r10; removes
// the ~60us of inter-node/launch-drain overhead seen in the dur_us-vs-kernel-
// sum accounting. Fallback to the 3-kernel r10 path if coop launch fails.
//
// ws (floats): cost[1048576] | nssu|lziu|nssv|lziv (262144 ea) |
//              parts[2048] | gamma u32x2[4096*64*64] (134MB)

typedef __attribute__((ext_vector_type(8))) _Float16 half8;
typedef __attribute__((ext_vector_type(8))) short short8;
typedef __attribute__((ext_vector_type(4))) float f32x4;
typedef __attribute__((ext_vector_type(2))) unsigned int u32x2;

__device__ __forceinline__ float fexp2(float x) { return __builtin_amdgcn_exp2f(x); }

__device__ __forceinline__ half8 ldsh8(const unsigned short* p) {
  return __builtin_bit_cast(half8, *(const short8*)p);
}

__device__ __forceinline__ unsigned bf16r(float f) {   // bf16 RNE, low 16 bits
  unsigned u = __float_as_uint(f);
  return (u + 0x7FFFu + ((u >> 16) & 1u)) >> 16;
}

__device__ __forceinline__ int tswz(int row, int g) {  // swizzled table offset
  return row * 32 + (((g + (row >> 1)) & 3) << 3);
}

// LDS layout (bytes), aliased across phases (phases separated by syncs):
//  [0,4096)      : nssU/lzU/nssV/lzV (4x256 f32)     | phase0: smemAll[512] | phaseB: w_all[1024]
//  [4096,4128)   : red[8]
//  [4128,12320)  : EU0   [12320,20512): EU1
//  [20512,36896) : EV0   [36896,53280): EV1
#define LDS_BYTES 53280

// ---------------- phase 0 units (256-thread sub-blocks) ----------------
__device__ __forceinline__ void cost_unit(int u, int tid, float* smemAll,
                                          const float* __restrict__ X,
                                          const float* __restrict__ Y,
                                          float* __restrict__ cost) {
  const int half = tid >> 8, t = tid & 255;
  float* smem = smemAll + half*256;
  const int jq = u & 63, bh = u >> 6;
  const int j0 = jq * 4;
  __syncthreads();                       // guard previous iteration's readers
  smem[t] = X[((size_t)bh*256 + j0 + (t >> 6))*64 + (t & 63)];
  __syncthreads();
  const float4* yp = (const float4*)(Y + ((size_t)bh*256 + t)*64);
  float dot[4] = {0.f,0.f,0.f,0.f}, x2[4] = {0.f,0.f,0.f,0.f}, y2 = 0.f;
#pragma unroll
  for (int q = 0; q < 16; ++q) {
    float4 yv = yp[q];
    y2 += yv.x*yv.x + yv.y*yv.y + yv.z*yv.z + yv.w*yv.w;
#pragma unroll
    for (int r = 0; r < 4; ++r) {
      float4 xv = ((const float4*)(smem + r*64))[q];
      dot[r] += xv.x*yv.x + xv.y*yv.y + xv.z*yv.z + xv.w*yv.w;
      x2[r]  += xv.x*xv.x + xv.y*xv.y + xv.z*xv.z + xv.w*xv.w;
    }
  }
#pragma unroll
  for (int r = 0; r < 4; ++r) {
    float c = x2[r] + y2 - 2.f*dot[r];
    cost[((size_t)bh*256 + j0 + r)*256 + t] = sqrtf(fmaxf(c, 1e-12f));
  }
}

__device__ __forceinline__ void sortz_unit(int u, int tid, float* smemAll,
                                           const float* __restrict__ X,
                                           const float* __restrict__ Y,
                                           float* __restrict__ nssu, float* __restrict__ lziu,
                                           float* __restrict__ nssv, float* __restrict__ lziv) {
  const int half = tid >> 8, t = tid & 255;
  float* s = smemAll + half*256;
  const int l = u & 63, bh = (u >> 6) & 15, uv = u >> 10;
  const float* S = uv ? Y : X;
  float* so = uv ? nssv : nssu;
  float* zo = uv ? lziv : lziu;
  float v = S[((size_t)bh*256 + t)*64 + l];
  __syncthreads();                       // guard previous iteration's readers
#pragma unroll
  for (int k = 2; k <= 256; k <<= 1) {
#pragma unroll
    for (int j = k >> 1; j > 0; j >>= 1) {
      float o;
      if (j >= 64) {
        s[t] = v; __syncthreads();
        o = s[t ^ j]; __syncthreads();
      } else {
        o = __shfl_xor(v, j, 64);
      }
      const bool up    = ((t & k) == 0);
      const bool lower = ((t & j) == 0);
      float mn = fminf(v, o), mx = fmaxf(v, o);
      v = (up == lower) ? mn : mx;
    }
  }
  s[t] = v; __syncthreads();
  const int jc = 255 - t;
  const float sv = s[jc];
  const int lo = jc > 48 ? jc - 48 : 0;
  const int hi = jc < 207 ? jc + 48 : 255;
  float z = 0.f;
  for (int jj = lo; jj <= hi; ++jj) { float d = s[jj] - sv; z += fexp2(d*d*CEXP); }
  const int base = (bh*64 + l)*256 + t;
  so[base] = -SQRTC * sv; zo[base] = -__log2f(z);
}

// ---------------- staging (identical to r10) ----------------
__device__ __forceinline__ void stage_slab(int t, int ib, float usc, float vsc,
                                           const float* __restrict__ nssU, const float* __restrict__ lzU,
                                           const float* __restrict__ nssV, const float* __restrict__ lzV,
                                           unsigned short* __restrict__ EU,
                                           unsigned short* __restrict__ EV) {
  {
    const int r = t & 127, g = t >> 7;
    const int i0 = ib + (g << 3);
    float e[8];
#pragma unroll
    for (int ii = 0; ii < 8; ++ii) {
      float d = usc + nssU[i0 + ii];
      e[ii] = fexp2(fmaf(-d, d, lzU[i0 + ii]));
    }
    uint4 w;
    w.x = __builtin_bit_cast(unsigned, __builtin_amdgcn_cvt_pkrtz(e[0], e[1]));
    w.y = __builtin_bit_cast(unsigned, __builtin_amdgcn_cvt_pkrtz(e[2], e[3]));
    w.z = __builtin_bit_cast(unsigned, __builtin_amdgcn_cvt_pkrtz(e[4], e[5]));
    w.w = __builtin_bit_cast(unsigned, __builtin_amdgcn_cvt_pkrtz(e[6], e[7]));
    *(uint4*)&EU[tswz(r, g)] = w;
  }
  {
    const int r = t & 255;
    const int gp = (t >> 8) << 1;
#pragma unroll
    for (int gg = 0; gg < 2; ++gg) {
      const int i0 = ib + ((gp + gg) << 3);
      float e[8];
#pragma unroll
      for (int ii = 0; ii < 8; ++ii) {
        float d = vsc + nssV[i0 + ii];
        e[ii] = fexp2(fmaf(-d, d, lzV[i0 + ii]));
      }
      uint4 w;
      w.x = __builtin_bit_cast(unsigned, __builtin_amdgcn_cvt_pkrtz(e[0], e[1]));
      w.y = __builtin_bit_cast(unsigned, __builtin_amdgcn_cvt_pkrtz(e[2], e[3]));
      w.z = __builtin_bit_cast(unsigned, __builtin_amdgcn_cvt_pkrtz(e[4], e[5]));
      w.w = __builtin_bit_cast(unsigned, __builtin_amdgcn_cvt_pkrtz(e[6], e[7]));
      *(uint4*)&EV[tswz(r, gp + gg)] = w;
    }
  }
}

// ---------------- pass1 unit (identical inner loop to r10) ----------------
__device__ __forceinline__ void pass1_unit(int unit, int tid, unsigned char* lds,
    const float* __restrict__ X, const float* __restrict__ Y,
    const float* __restrict__ cost,
    const float* __restrict__ nssu, const float* __restrict__ lziu,
    const float* __restrict__ nssv, const float* __restrict__ lziv,
    float* __restrict__ parts, u32x2* __restrict__ gamma) {
  float* nssU = (float*)lds;
  float* lzU  = nssU + 256;
  float* nssV = lzU + 256;
  float* lzV  = nssV + 256;
  float* red  = (float*)(lds + 4096);
  unsigned short* EU0 = (unsigned short*)(lds + 4128);
  unsigned short* EU1 = (unsigned short*)(lds + 12320);
  unsigned short* EV0 = (unsigned short*)(lds + 20512);
  unsigned short* EV1 = (unsigned short*)(lds + 36896);

  const int sb = unit & 1, l = (unit >> 1) & 63, bh = unit >> 7;
  const int j0 = sb * 128;
  const int wave = tid >> 6, lane = tid & 63;
  const int wj = (wave & 1) * 64, wk = (wave >> 1) * 64;
  const int m = lane & 15, q = lane >> 4;
  const int inner = m*32 + (((q + (m >> 1)) & 3) << 3);

  const int lb = (bh*64 + l)*256;
  const float usc = SQRTC * X[((size_t)bh*256 + j0 + (tid & 127))*64 + l];
  const float vsc = SQRTC * Y[((size_t)bh*256 + (tid & 255))*64 + l];
  __syncthreads();                       // guard previous unit's LDS readers
  if (tid < 256) { nssU[tid] = nssu[lb + tid]; lzU[tid] = lziu[lb + tid]; }
  else { const int t2 = tid - 256; nssV[t2] = nssv[lb + t2]; lzV[t2] = lziv[lb + t2]; }

  f32x4 acc[16];
#pragma unroll
  for (int t = 0; t < 16; ++t) acc[t] = (f32x4){0.f, 0.f, 0.f, 0.f};

  __syncthreads();
  stage_slab(tid, 0, usc, vsc, nssU, lzU, nssV, lzV, EU0, EV0);
  __syncthreads();
#pragma unroll 1
  for (int s = 0; s < 8; ++s) {
    const unsigned short* EUc = (s & 1) ? EU1 : EU0;
    const unsigned short* EVc = (s & 1) ? EV1 : EV0;
    unsigned short* EUn = (s & 1) ? EU0 : EU1;
    unsigned short* EVn = (s & 1) ? EV0 : EV1;
    half8 A[4], B[4];
#pragma unroll
    for (int mt = 0; mt < 4; ++mt) A[mt] = ldsh8(&EUc[(wj + mt*16)*32 + inner]);
#pragma unroll
    for (int nt = 0; nt < 4; ++nt) B[nt] = ldsh8(&EVc[(wk + nt*16)*32 + inner]);
    if (s < 7)
      stage_slab(tid, (s+1)*32, usc, vsc, nssU, lzU, nssV, lzV, EUn, EVn);
#pragma unroll
    for (int mt = 0; mt < 4; ++mt)
#pragma unroll
      for (int nt = 0; nt < 4; ++nt)
        acc[mt*4+nt] = __builtin_amdgcn_mfma_f32_16x16x32_f16(A[mt], B[nt], acc[mt*4+nt], 0, 0, 0);
    __syncthreads();
  }

  // epilogue: dot with cost + coalesced NT bf16 Gamma store.
  const float* cb = cost + (size_t)bh * 65536;
  const int gbase = ((bh*2 + sb)*8 + wave) * 16;
  float part = 0.f;
#pragma unroll
  for (int mt = 0; mt < 4; ++mt) {
#pragma unroll
    for (int nt = 0; nt < 4; ++nt) {
      const int col  = wk + nt*16 + m;
      const int rowb = j0 + wj + mt*16 + q*4;
      f32x4 a = acc[mt*4 + nt];
      part += a.x*cb[(size_t)(rowb+0)*256 + col] + a.y*cb[(size_t)(rowb+1)*256 + col]
            + a.z*cb[(size_t)(rowb+2)*256 + col] + a.w*cb[(size_t)(rowb+3)*256 + col];
      u32x2 pk;
      pk.x = bf16r(a.x) | (bf16r(a.y) << 16);
      pk.y = bf16r(a.z) | (bf16r(a.w) << 16);
      __builtin_nontemporal_store(pk, &gamma[((size_t)(gbase + mt*4 + nt)*64 + l)*64 + lane]);
    }
  }
#pragma unroll
  for (int o = 32; o > 0; o >>= 1) part += __shfl_down(part, o, 64);
  if (lane == 0) red[wave] = part;
  __syncthreads();
  if (tid == 0) {
    parts[sb*1024 + bh*64 + l] =
        red[0]+red[1]+red[2]+red[3]+red[4]+red[5]+red[6]+red[7];
  }
}

// ---------------- phase B units ----------------
__device__ __forceinline__ void weights_all(int tid, float* w_all,
                                            const float* __restrict__ parts) {
  const int wv = tid >> 6, lane = tid & 63;
#pragma unroll
  for (int it = 0; it < 2; ++it) {
    const int bh = wv + it*8;
    float s = parts[bh*64 + lane] + parts[1024 + bh*64 + lane];
    float v = -TEMP * s * LOG2E;
    float mx = v;
#pragma unroll
    for (int o = 32; o > 0; o >>= 1) mx = fmaxf(mx, __shfl_xor(mx, o, 64));
    float e = fexp2(v - mx);
    float ssum = e;
#pragma unroll
    for (int o = 32; o > 0; o >>= 1) ssum += __shfl_xor(ssum, o, 64);
    w_all[bh*64 + lane] = e / ssum;
  }
}

__device__ __forceinline__ void wsum_group(int group, int lane, const float* w_all,
                                           const u32x2* __restrict__ g,
                                           float* __restrict__ out) {
  const int frag = group & 15;
  const int idx  = group >> 4;                 // (bh*2+sb)*8 + wave
  const int wave = idx & 7, sbb = (idx >> 3) & 1, bh = idx >> 4;
  const float* w = w_all + bh*64;
  const u32x2* gp = g + (size_t)group*4096 + lane;
  float4 acc = {0.f, 0.f, 0.f, 0.f};
#pragma unroll 8
  for (int l = 0; l < 64; ++l) {
    u32x2 pk = __builtin_nontemporal_load(gp + l*64);
    float wl = w[l];
    acc.x += wl * __uint_as_float(pk.x << 16);
    acc.y += wl * __uint_as_float(pk.x & 0xFFFF0000u);
    acc.z += wl * __uint_as_float(pk.y << 16);
    acc.w += wl * __uint_as_float(pk.y & 0xFFFF0000u);
  }
  const int mt = frag >> 2, nt = frag & 3;
  const int m = lane & 15, q = lane >> 4;
  const int row = sbb*128 + (wave & 1)*64 + mt*16 + q*4;
  const int col = (wave >> 1)*64 + nt*16 + m;
  float* ob = out + ((size_t)bh*256 + row)*256 + col;
  __builtin_nontemporal_store(acc.x, &ob[0]);
  __builtin_nontemporal_store(acc.y, &ob[256]);
  __builtin_nontemporal_store(acc.z, &ob[512]);
  __builtin_nontemporal_store(acc.w, &ob[768]);
}

// ---------------- fused cooperative kernel ----------------
__global__ __launch_bounds__(512, 4) void fused_kernel(
    const float* __restrict__ X, const float* __restrict__ Y,
    float* __restrict__ cost,
    float* __restrict__ nssu, float* __restrict__ lziu,
    float* __restrict__ nssv, float* __restrict__ lziv,
    float* __restrict__ parts, u32x2* __restrict__ gamma,
    float* __restrict__ out) {
  __shared__ __align__(16) unsigned char lds[LDS_BYTES];
  const int tid = threadIdx.x;
  float* smemAll = (float*)lds;

  // phase 0: prep (two 256-thread sub-blocks per block; uniform barrier counts)
  {
    const int nsub = gridDim.x * 2;
    const int sub0 = blockIdx.x*2 + (tid >> 8);
    const int it1 = (1024 + nsub - 1) / nsub;
    for (int it = 0; it < it1; ++it) {
      int u = sub0 + it*nsub; if (u > 1023) u = 1023;   // clamp: duplicate stores benign
      cost_unit(u, tid, smemAll, X, Y, cost);
    }
    const int it2 = (2048 + nsub - 1) / nsub;
    for (int it = 0; it < it2; ++it) {
      int u = sub0 + it*nsub; if (u > 2047) u = 2047;
      sortz_unit(u, tid, smemAll, X, Y, nssu, lziu, nssv, lziv);
    }
  }
  cg::this_grid().sync();

  // phase A: pass1 units (grid-strided)
  {
    const int iters = (2048 + gridDim.x - 1) / gridDim.x;
    for (int it = 0; it < iters; ++it) {
      int u = blockIdx.x + it*gridDim.x; if (u > 2047) u = 2047;
      pass1_unit(u, tid, lds, X, Y, cost, nssu, lziu, nssv, lziv, parts, gamma);
    }
  }
  cg::this_grid().sync();

  // phase B: weights (redundant per block) + wsum groups
  {
    float* w_all = (float*)lds;
    weights_all(tid, w_all, parts);
    __syncthreads();
    const int wv = tid >> 6, lane = tid & 63;
    const int nwu = gridDim.x * 8;
    const int iters = (4096 + nwu - 1) / nwu;
    for (int it = 0; it < iters; ++it) {
      int gidx = blockIdx.x*8 + wv + it*nwu; if (gidx > 4095) gidx = 4095;
      wsum_group(gidx, lane, w_all, gamma, out);
    }
  }
}

// ---------------- fallback 3-kernel path (r10-equivalent) ----------------
__global__ __launch_bounds__(512) void k_prep(const float* __restrict__ X,
                                              const float* __restrict__ Y,
                                              float* __restrict__ cost,
                                              float* __restrict__ nssu, float* __restrict__ lziu,
                                              float* __restrict__ nssv, float* __restrict__ lziv) {
  __shared__ __align__(16) float smemAll[512];
  const int sub = blockIdx.x*2 + (threadIdx.x >> 8);   // 1024 even -> block-uniform branch
  if (sub < 1024) cost_unit(sub, threadIdx.x, smemAll, X, Y, cost);
  else            sortz_unit(sub - 1024, threadIdx.x, smemAll, X, Y, nssu, lziu, nssv, lziv);
}

__global__ __launch_bounds__(512, 4) void k_pass1(
    const float* __restrict__ X, const float* __restrict__ Y,
    const float* __restrict__ cost,
    const float* __restrict__ nssu, const float* __restrict__ lziu,
    const float* __restrict__ nssv, const float* __restrict__ lziv,
    float* __restrict__ parts, u32x2* __restrict__ gamma) {
  __shared__ __align__(16) unsigned char lds[LDS_BYTES];
  pass1_unit(blockIdx.x, threadIdx.x, lds, X, Y, cost, nssu, lziu, nssv, lziv, parts, gamma);
}

__global__ __launch_bounds__(512) void k_wsum(const u32x2* __restrict__ g,
                                              const float* __restrict__ parts,
                                              float* __restrict__ out) {
  __shared__ float w_all[1024];
  weights_all(threadIdx.x, w_all, parts);
  __syncthreads();
  wsum_group(blockIdx.x*8 + (threadIdx.x >> 6), threadIdx.x & 63, w_all, g, out);
}

extern "C" void kernel_launch(void* const* d_in, const int* in_sizes, int n_in,
                              void* d_out, int out_size, void* d_ws, size_t ws_size,
                              hipStream_t stream) {
  (void)in_sizes; (void)n_in; (void)out_size; (void)ws_size;
  const float* X = (const float*)d_in[0];
  const float* Y = (const float*)d_in[1];
  float* out = (float*)d_out;
  float* ws  = (float*)d_ws;
  float* cost  = ws;                    // 1048576
  float* nssu  = ws   + 1048576;
  float* lziu  = nssu + 262144;
  float* nssv  = lziu + 262144;
  float* lziv  = nssv + 262144;
  float* parts = lziv + 262144;         // 2048
  u32x2* gamma = (u32x2*)(parts + 2048);// 134MB

  // occupancy-derived cooperative grid (computed once; constant per process)
  static int coop_grid = -1;
  if (coop_grid < 0) {
    int occ = 0;
    hipError_t e = hipOccupancyMaxActiveBlocksPerMultiprocessor(&occ, fused_kernel, 512, 0);
    int g = (e == hipSuccess) ? occ * 256 : 0;   // 256 CUs on MI355X
    if (g > 512) g = 512;
    coop_grid = g;                                // 0 -> fallback path
  }

  bool done = false;
  if (coop_grid > 0) {
    void* args[] = { (void*)&X, (void*)&Y, (void*)&cost,
                     (void*)&nssu, (void*)&lziu, (void*)&nssv, (void*)&lziv,
                     (void*)&parts, (void*)&gamma, (void*)&out };
    hipError_t e = hipLaunchCooperativeKernel((const void*)fused_kernel,
                                              dim3(coop_grid), dim3(512),
                                              args, 0, stream);
    done = (e == hipSuccess);
  }
  if (!done) {
    k_prep <<<dim3(1536),       512, 0, stream>>>(X, Y, cost, nssu, lziu, nssv, lziv);
    k_pass1<<<dim3(2048),       512, 0, stream>>>(X, Y, cost, nssu, lziu, nssv, lziv,
                                                  parts, gamma);
    k_wsum <<<dim3(512),        512, 0, stream>>>(gamma, parts, out);
  }
}

// Round 12
// 163.331 us; speedup vs baseline: 2.1247x; 2.1247x over previous
//
#include <hip/hip_runtime.h>
#include <math.h>

#define TEMP    0.1f
#define CEXP    -1442.6950408889634f   // -1000 * log2(e)
#define SQRTC   37.98283767f           // sqrt(1000 * log2(e))
#define LOG2E   1.4426950408889634f

// Problem: B=2,H=8 -> BH=16; N=256; L=64.  X,Y: [BH,256,64] f32. out: [BH,256,256] f32.
//
// Round 12: exact r10 structure (known-good 162.8us) with ONE change: gamma
// store/load are plain (cached) accesses instead of non-temporal. gamma=134MB
// fits the 256MB Infinity Cache; NT was forcing the full round trip to HBM and
// making wsum latency-bound. NT kept only on final out stores.
//
// ws (floats): cost[1048576] | nssu|lziu|nssv|lziv (262144 ea) |
//              parts[2048] | gamma u32x2[4096*64*64] (134MB)

typedef __attribute__((ext_vector_type(8))) _Float16 half8;
typedef __attribute__((ext_vector_type(8))) short short8;
typedef __attribute__((ext_vector_type(4))) float f32x4;
typedef __attribute__((ext_vector_type(2))) unsigned int u32x2;

__device__ __forceinline__ float fexp2(float x) { return __builtin_amdgcn_exp2f(x); }

__device__ __forceinline__ half8 ldsh8(const unsigned short* p) {
  return __builtin_bit_cast(half8, *(const short8*)p);
}

__device__ __forceinline__ unsigned bf16r(float f) {   // bf16 RNE, low 16 bits
  unsigned u = __float_as_uint(f);
  return (u + 0x7FFFu + ((u >> 16) & 1u)) >> 16;
}

// swizzled short-offset of (row, oct g) in a 32-short-per-row table
__device__ __forceinline__ int tswz(int row, int g) {
  return row * 32 + (((g + (row >> 1)) & 3) << 3);
}

// prep: blockIdx.x < 1024 -> cost quad-row tile; else sortz for (l, bh, X/Y).
// sortz stores nss = -SQRTC*sorted_val and lz = -log2(Z) (banded Z, tail<e^-60).
__global__ __launch_bounds__(256) void prep_kernel(const float* __restrict__ X,
                                                   const float* __restrict__ Y,
                                                   float* __restrict__ cost,
                                                   float* __restrict__ nssu, float* __restrict__ lziu,
                                                   float* __restrict__ nssv, float* __restrict__ lziv) {
  __shared__ __align__(16) float smem[256];
  const int tid = threadIdx.x;
  if (blockIdx.x < 1024) {
    const int jq = blockIdx.x & 63, bh = blockIdx.x >> 6;
    const int j0 = jq * 4;
    smem[tid] = X[((size_t)bh*256 + j0 + (tid >> 6))*64 + (tid & 63)];
    __syncthreads();
    const float4* yp = (const float4*)(Y + ((size_t)bh*256 + tid)*64);
    float dot[4] = {0.f,0.f,0.f,0.f}, x2[4] = {0.f,0.f,0.f,0.f}, y2 = 0.f;
#pragma unroll
    for (int t = 0; t < 16; ++t) {
      float4 yv = yp[t];
      y2 += yv.x*yv.x + yv.y*yv.y + yv.z*yv.z + yv.w*yv.w;
#pragma unroll
      for (int r = 0; r < 4; ++r) {
        float4 xv = ((const float4*)(smem + r*64))[t];
        dot[r] += xv.x*yv.x + xv.y*yv.y + xv.z*yv.z + xv.w*yv.w;
        x2[r]  += xv.x*xv.x + xv.y*xv.y + xv.z*xv.z + xv.w*xv.w;
      }
    }
#pragma unroll
    for (int r = 0; r < 4; ++r) {
      float c = x2[r] + y2 - 2.f*dot[r];
      cost[((size_t)bh*256 + j0 + r)*256 + tid] = sqrtf(fmaxf(c, 1e-12f));
    }
  } else {
    const int idx = blockIdx.x - 1024;
    const int l = idx & 63, bh = (idx >> 6) & 15, uv = idx >> 10;
    const float* S = uv ? Y : X;
    float* so = uv ? nssv : nssu;
    float* zo = uv ? lziv : lziu;
    float v = S[((size_t)bh*256 + tid)*64 + l];
#pragma unroll
    for (int k = 2; k <= 256; k <<= 1) {
#pragma unroll
      for (int j = k >> 1; j > 0; j >>= 1) {
        float o;
        if (j >= 64) {
          smem[tid] = v; __syncthreads();
          o = smem[tid ^ j]; __syncthreads();
        } else {
          o = __shfl_xor(v, j, 64);
        }
        const bool up    = ((tid & k) == 0);
        const bool lower = ((tid & j) == 0);
        float mn = fminf(v, o), mx = fmaxf(v, o);
        v = (up == lower) ? mn : mx;
      }
    }
    smem[tid] = v; __syncthreads();
    const int jc = 255 - tid;
    const float sv = smem[jc];
    const int lo = jc > 48 ? jc - 48 : 0;
    const int hi = jc < 207 ? jc + 48 : 255;
    float z = 0.f;
    for (int jj = lo; jj <= hi; ++jj) { float d = smem[jj] - sv; z += fexp2(d*d*CEXP); }
    const int base = (bh*64 + l)*256 + tid;
    so[base] = -SQRTC * sv; zo[base] = -__log2f(z);
  }
}

// stage one 32-i slab (512 threads): EU (128 rows): thread t -> row t&127,
// oct t>>7 (8 entries). EV (256 rows): row t&255, octs (t>>8)*2+{0,1} (16).
// Entry: d = usc + nss_i; e = exp2(fma(-d,d,lz_i)).  3 VALU ops/entry.
__device__ __forceinline__ void stage_slab(int t, int ib, float usc, float vsc,
                                           const float* __restrict__ nssU, const float* __restrict__ lzU,
                                           const float* __restrict__ nssV, const float* __restrict__ lzV,
                                           unsigned short* __restrict__ EU,
                                           unsigned short* __restrict__ EV) {
  {
    const int r = t & 127, g = t >> 7;
    const int i0 = ib + (g << 3);
    float e[8];
#pragma unroll
    for (int ii = 0; ii < 8; ++ii) {
      float d = usc + nssU[i0 + ii];
      e[ii] = fexp2(fmaf(-d, d, lzU[i0 + ii]));
    }
    uint4 w;
    w.x = __builtin_bit_cast(unsigned, __builtin_amdgcn_cvt_pkrtz(e[0], e[1]));
    w.y = __builtin_bit_cast(unsigned, __builtin_amdgcn_cvt_pkrtz(e[2], e[3]));
    w.z = __builtin_bit_cast(unsigned, __builtin_amdgcn_cvt_pkrtz(e[4], e[5]));
    w.w = __builtin_bit_cast(unsigned, __builtin_amdgcn_cvt_pkrtz(e[6], e[7]));
    *(uint4*)&EU[tswz(r, g)] = w;
  }
  {
    const int r = t & 255;
    const int gp = (t >> 8) << 1;
#pragma unroll
    for (int gg = 0; gg < 2; ++gg) {
      const int i0 = ib + ((gp + gg) << 3);
      float e[8];
#pragma unroll
      for (int ii = 0; ii < 8; ++ii) {
        float d = vsc + nssV[i0 + ii];
        e[ii] = fexp2(fmaf(-d, d, lzV[i0 + ii]));
      }
      uint4 w;
      w.x = __builtin_bit_cast(unsigned, __builtin_amdgcn_cvt_pkrtz(e[0], e[1]));
      w.y = __builtin_bit_cast(unsigned, __builtin_amdgcn_cvt_pkrtz(e[2], e[3]));
      w.z = __builtin_bit_cast(unsigned, __builtin_amdgcn_cvt_pkrtz(e[4], e[5]));
      w.w = __builtin_bit_cast(unsigned, __builtin_amdgcn_cvt_pkrtz(e[6], e[7]));
      *(uint4*)&EV[tswz(r, gp + gg)] = w;
    }
  }
}

// Pass 1: per (strip sb, l, bh): 128j x 256k Gamma strip via pipelined fp16
// MFMA (8 waves, 64x64 wave tiles, acc[16]); dot with cost -> parts; Gamma
// bf16 store (cached — gamma fits the 256MB L3) fragment-linear [group][l][lane].
__global__ __launch_bounds__(512, 4) void pass1_kernel(
    const float* __restrict__ X, const float* __restrict__ Y,
    const float* __restrict__ cost,
    const float* __restrict__ nssu, const float* __restrict__ lziu,
    const float* __restrict__ nssv, const float* __restrict__ lziv,
    float* __restrict__ parts, u32x2* __restrict__ gamma) {
  const int sb = blockIdx.x, l = blockIdx.y, bh = blockIdx.z;
  const int j0 = sb * 128;
  const int tid = threadIdx.x, wave = tid >> 6, lane = tid & 63;
  const int wj = (wave & 1) * 64, wk = (wave >> 1) * 64;
  const int m = lane & 15, q = lane >> 4;
  const int inner = m*32 + (((q + (m >> 1)) & 3) << 3);

  __shared__ float nssU[256], lzU[256], nssV[256], lzV[256];
  __shared__ __align__(16) unsigned short EU0[128*32], EU1[128*32];
  __shared__ __align__(16) unsigned short EV0[256*32], EV1[256*32];
  __shared__ float red[8];
  // LDS: 4KB + 16KB + 32KB = 52.2KB -> 2 blocks/CU x 8 waves = 4 waves/SIMD

  const int lb = (bh*64 + l)*256;
  const float usc = SQRTC * X[((size_t)bh*256 + j0 + (tid & 127))*64 + l];
  const float vsc = SQRTC * Y[((size_t)bh*256 + (tid & 255))*64 + l];
  if (tid < 256) { nssU[tid] = nssu[lb + tid]; lzU[tid] = lziu[lb + tid]; }
  else { const int t2 = tid - 256; nssV[t2] = nssv[lb + t2]; lzV[t2] = lziv[lb + t2]; }

  f32x4 acc[16];
#pragma unroll
  for (int t = 0; t < 16; ++t) acc[t] = (f32x4){0.f, 0.f, 0.f, 0.f};

  __syncthreads();
  stage_slab(tid, 0, usc, vsc, nssU, lzU, nssV, lzV, EU0, EV0);
  __syncthreads();
#pragma unroll 1
  for (int s = 0; s < 8; ++s) {
    const unsigned short* EUc = (s & 1) ? EU1 : EU0;
    const unsigned short* EVc = (s & 1) ? EV1 : EV0;
    unsigned short* EUn = (s & 1) ? EU0 : EU1;
    unsigned short* EVn = (s & 1) ? EV0 : EV1;
    half8 A[4], B[4];
#pragma unroll
    for (int mt = 0; mt < 4; ++mt) A[mt] = ldsh8(&EUc[(wj + mt*16)*32 + inner]);
#pragma unroll
    for (int nt = 0; nt < 4; ++nt) B[nt] = ldsh8(&EVc[(wk + nt*16)*32 + inner]);
    if (s < 7)
      stage_slab(tid, (s+1)*32, usc, vsc, nssU, lzU, nssV, lzV, EUn, EVn);
#pragma unroll
    for (int mt = 0; mt < 4; ++mt)
#pragma unroll
      for (int nt = 0; nt < 4; ++nt)
        acc[mt*4+nt] = __builtin_amdgcn_mfma_f32_16x16x32_f16(A[mt], B[nt], acc[mt*4+nt], 0, 0, 0);
    __syncthreads();
  }

  // epilogue: dot with cost + coalesced cached bf16 Gamma store.
  // C/D map: col=lane&15, row=(lane>>4)*4+reg
  const float* cb = cost + (size_t)bh * 65536;
  const int gbase = ((bh*2 + sb)*8 + wave) * 16;
  float part = 0.f;
#pragma unroll
  for (int mt = 0; mt < 4; ++mt) {
#pragma unroll
    for (int nt = 0; nt < 4; ++nt) {
      const int col  = wk + nt*16 + m;
      const int rowb = j0 + wj + mt*16 + q*4;
      f32x4 a = acc[mt*4 + nt];
      part += a.x*cb[(size_t)(rowb+0)*256 + col] + a.y*cb[(size_t)(rowb+1)*256 + col]
            + a.z*cb[(size_t)(rowb+2)*256 + col] + a.w*cb[(size_t)(rowb+3)*256 + col];
      u32x2 pk;
      pk.x = bf16r(a.x) | (bf16r(a.y) << 16);
      pk.y = bf16r(a.z) | (bf16r(a.w) << 16);
      gamma[((size_t)(gbase + mt*4 + nt)*64 + l)*64 + lane] = pk;   // cached (L3-resident)
    }
  }
#pragma unroll
  for (int o = 32; o > 0; o >>= 1) part += __shfl_down(part, o, 64);
  if (lane == 0) red[wave] = part;
  __syncthreads();
  if (tid == 0) {
    float s8 = red[0]+red[1]+red[2]+red[3]+red[4]+red[5]+red[6]+red[7];
    parts[sb*1024 + bh*64 + l] = s8;
  }
}

// wsum: per block, recompute softmax weights from the 2 swds partials, then
// out = sum_l w_l * Gamma_l (each wave streams one 32KB fragment-linear chunk,
// cached loads — gamma should be L3-resident).
__global__ __launch_bounds__(256) void wsum_kernel(const u32x2* __restrict__ g,
                                                   const float* __restrict__ parts,
                                                   float* __restrict__ out) {
  const int wv = threadIdx.x >> 6, lane = threadIdx.x & 63;
  const int bh = blockIdx.x >> 6;                 // 64 blocks per bh (uniform)
  __shared__ float w[64];
  if (wv == 0) {
    float s = parts[bh*64 + lane] + parts[1024 + bh*64 + lane];
    float v = -TEMP * s * LOG2E;                  // log2-domain logits
    float mx = v;
#pragma unroll
    for (int o = 32; o > 0; o >>= 1) mx = fmaxf(mx, __shfl_xor(mx, o, 64));
    float e = fexp2(v - mx);
    float ssum = e;
#pragma unroll
    for (int o = 32; o > 0; o >>= 1) ssum += __shfl_xor(ssum, o, 64);
    w[lane] = e / ssum;
  }
  __syncthreads();
  const int group = blockIdx.x * 4 + wv;
  const u32x2* gp = g + (size_t)group*4096 + lane;
  float4 acc = {0.f, 0.f, 0.f, 0.f};
#pragma unroll 8
  for (int l = 0; l < 64; ++l) {
    u32x2 pk = gp[l*64];                          // cached load
    float wl = w[l];
    acc.x += wl * __uint_as_float(pk.x << 16);
    acc.y += wl * __uint_as_float(pk.x & 0xFFFF0000u);
    acc.z += wl * __uint_as_float(pk.y << 16);
    acc.w += wl * __uint_as_float(pk.y & 0xFFFF0000u);
  }
  const int frag = group & 15;
  const int idx  = group >> 4;                    // (bh*2+sb)*8 + wave
  const int wave = idx & 7, sbb = (idx >> 3) & 1;
  const int mt = frag >> 2, nt = frag & 3;
  const int m = lane & 15, q = lane >> 4;
  const int row = sbb*128 + (wave & 1)*64 + mt*16 + q*4;
  const int col = (wave >> 1)*64 + nt*16 + m;
  float* ob = out + ((size_t)bh*256 + row)*256 + col;
  __builtin_nontemporal_store(acc.x, &ob[0]);     // out is write-once: NT stays
  __builtin_nontemporal_store(acc.y, &ob[256]);
  __builtin_nontemporal_store(acc.z, &ob[512]);
  __builtin_nontemporal_store(acc.w, &ob[768]);
}

extern "C" void kernel_launch(void* const* d_in, const int* in_sizes, int n_in,
                              void* d_out, int out_size, void* d_ws, size_t ws_size,
                              hipStream_t stream) {
  (void)in_sizes; (void)n_in; (void)out_size; (void)ws_size;
  const float* X = (const float*)d_in[0];
  const float* Y = (const float*)d_in[1];
  float* out = (float*)d_out;
  float* ws  = (float*)d_ws;
  float* cost  = ws;                    // 1048576
  float* nssu  = ws   + 1048576;
  float* lziu  = nssu + 262144;
  float* nssv  = lziu + 262144;
  float* lziv  = nssv + 262144;
  float* parts = lziv + 262144;         // 2048 (written, not accumulated)
  u32x2* gamma = (u32x2*)(parts + 2048);// 4096 groups x 64 l x 64 lanes x 8B = 134MB

  prep_kernel <<<dim3(3072),      256, 0, stream>>>(X, Y, cost, nssu, lziu, nssv, lziv);
  pass1_kernel<<<dim3(2, 64, 16), 512, 0, stream>>>(X, Y, cost, nssu, lziu, nssv, lziv,
                                                    parts, gamma);
  wsum_kernel <<<dim3(1024),      256, 0, stream>>>(gamma, parts, out);
}